// Round 15
// baseline (145.765 us; speedup 1.0000x reference)
//
#include <hip/hip_runtime.h>
#include <hip/hip_bf16.h>

// Sparse 3DNA (causal), MI355X. Round 22 (= R21 resubmitted after infra
// failure; source audited — no divergent barriers, no OOB, 14KB LDS).
// R17 GEMMs/prep (proven 121.9us). attn_v7 = v6's 2-queries-per-wave K/V
// sharing (0.66x logical L3 traffic) with the spill removed: raw scores go
// straight to LDS (attn_s) as produced, softmax runs IN LDS (64 threads,
// one per (q,g)), mix+PV unchanged from v6 (refcheck-passed math).
// v6's failure was pure register spill (VGPR 84 + 70MB scratch writes),
// not the sharing idea.

constexpr int TFR   = 8;
constexpr int SDIM  = 24;
constexpr int NVID  = TFR * SDIM * SDIM;   // 4608
constexpr int NTOK  = NVID + 1;            // 4609
constexpr int NH    = 8;
constexpr int DM    = 512;
constexpr int NJ    = 28;

typedef __attribute__((ext_vector_type(8))) short bf16x8;
typedef __attribute__((ext_vector_type(8))) unsigned short ushort8;
typedef __attribute__((ext_vector_type(4))) float f32x4;

typedef const __attribute__((address_space(1))) unsigned int* gas_ptr;
typedef __attribute__((address_space(3))) unsigned int* las_ptr;

__device__ __forceinline__ float bf2f(unsigned short u) {
    return __uint_as_float((unsigned)u << 16);
}
__device__ __forceinline__ unsigned short f2bf(float f) {
    __hip_bfloat16 h = __float2bfloat16(f);
    return reinterpret_cast<unsigned short&>(h);
}

// ---------------------------------------------------------------------------
// prep: transpose+cast Wq/Wkv and Wout; straight cast x -> xb (bf16).
// ---------------------------------------------------------------------------
__global__ __launch_bounds__(256)
void prep_w(const float* __restrict__ Wq, const float* __restrict__ Wkv,
            const float* __restrict__ Wout, const float* __restrict__ x,
            __hip_bfloat16* __restrict__ Wqkvt, __hip_bfloat16* __restrict__ Woutt,
            __hip_bfloat16* __restrict__ xb)
{
    const int tid = threadIdx.x;
    int tb = blockIdx.x;

    if (tb >= 1024) {                       // ---- x cast: fp32 -> bf16 ----
        const size_t base = (size_t)(tb - 1024) * 2048 + (size_t)tid * 8;
        if (base < (size_t)NTOK * DM) {
            const float4 f0 = *(const float4*)(x + base);
            const float4 f1 = *(const float4*)(x + base + 4);
            unsigned short v[8] = { f2bf(f0.x), f2bf(f0.y), f2bf(f0.z), f2bf(f0.w),
                                    f2bf(f1.x), f2bf(f1.y), f2bf(f1.z), f2bf(f1.w) };
            *(ushort8*)(xb + base) = *(const ushort8*)v;
        }
        return;
    }

    __shared__ float t[32][33];
    const float* W; __hip_bfloat16* Wt; int Nd, tX, rowOff;
    if (tb < 256)      { W = Wq;   Wt = Wqkvt; Nd = 512;  tX = 16; rowOff = 0;   }
    else if (tb < 768) { tb -= 256; W = Wkv;  Wt = Wqkvt; Nd = 1024; tX = 32; rowOff = 512; }
    else               { tb -= 768; W = Wout; Wt = Woutt; Nd = 512;  tX = 16; rowOff = 0;   }
    const int n0 = (tb % tX) * 32, k0 = (tb / tX) * 32;
    const int r  = tid >> 3;
    const int c4 = (tid & 7) * 4;
    const float4 v = *(const float4*)(W + (size_t)(k0 + r) * Nd + n0 + c4);
    t[r][c4 + 0] = v.x; t[r][c4 + 1] = v.y; t[r][c4 + 2] = v.z; t[r][c4 + 3] = v.w;
    __syncthreads();
    #pragma unroll
    for (int j = 0; j < 4; ++j)
        Wt[(size_t)(rowOff + n0 + r) * 512 + k0 + c4 + j] = __float2bfloat16(t[c4 + j][r]);
}

// ---------------------------------------------------------------------------
// QKV GEMM (R17): BM=BN=128, BK=64, 444 blocks, XCD-chunked, dbuf + vmcnt(8).
// ---------------------------------------------------------------------------
__global__ __launch_bounds__(256)
void gemm_qkv(const __hip_bfloat16* __restrict__ Ab, const __hip_bfloat16* __restrict__ Bt,
              float* __restrict__ Cq, __hip_bfloat16* __restrict__ Ckv, int M)
{
    constexpr int BM = 128, BN = 128, BK = 64, K = 512;
    __shared__ __align__(16) short As[2][BM * BK];
    __shared__ __align__(16) short Bs[2][BN * BK];

    const int tid  = threadIdx.x;
    const int bid  = blockIdx.x;
    const int xcd  = bid & 7, pos = bid >> 3;
    const int L    = (xcd < 4) ? xcd * 56 + pos : 224 + (xcd - 4) * 55 + pos;
    const int m0   = (L / 12) * BM;
    const int n0   = (L % 12) * BN;

    const int lane = tid & 63;
    const int wave = tid >> 6;
    const int wm   = (wave >> 1) * 64;
    const int wn   = (wave & 1) * 64;
    const int col  = lane & 15;
    const int quad = lane >> 4;

    f32x4 acc[4][4] = {};

    auto stage = [&](int buf, int k0) {
        #pragma unroll
        for (int it = 0; it < 4; ++it) {
            const int idx = it * 256 + tid;
            const int r   = idx >> 3;
            const int u   = (idx & 7) ^ (r & 7);
            const int gm  = (m0 + r < M) ? (m0 + r) : (M - 1);
            const __hip_bfloat16* gp = Ab + (size_t)gm * K + k0 + u * 8;
            __builtin_amdgcn_global_load_lds(
                (gas_ptr)gp, (las_ptr)&As[buf][(it * 256 + wave * 64) * 8], 16, 0, 0);
        }
        #pragma unroll
        for (int it = 0; it < 4; ++it) {
            const int idx = it * 256 + tid;
            const int r   = idx >> 3;
            const int u   = (idx & 7) ^ (r & 7);
            const __hip_bfloat16* gp = Bt + (size_t)(n0 + r) * K + k0 + u * 8;
            __builtin_amdgcn_global_load_lds(
                (gas_ptr)gp, (las_ptr)&Bs[buf][(it * 256 + wave * 64) * 8], 16, 0, 0);
        }
    };

    stage(0, 0);

    #pragma unroll
    for (int t = 0; t < K / BK; ++t) {
        const int cur = t & 1;
        if (t + 1 < K / BK) {
            stage(cur ^ 1, (t + 1) * BK);
            asm volatile("s_waitcnt vmcnt(8)" ::: "memory");   // cur's loads done
        } else {
            asm volatile("s_waitcnt vmcnt(0)" ::: "memory");
        }
        __builtin_amdgcn_s_barrier();

        #pragma unroll
        for (int ks = 0; ks < 2; ++ks) {
            bf16x8 af[4], bfr[4];
            #pragma unroll
            for (int mt = 0; mt < 4; ++mt) {
                const int r = wm + mt * 16 + col;
                const int u = (ks * 4 + quad) ^ (r & 7);
                af[mt] = *(const bf16x8*)(&As[cur][r * BK + u * 8]);
            }
            #pragma unroll
            for (int nt = 0; nt < 4; ++nt) {
                const int r = wn + nt * 16 + col;
                const int u = (ks * 4 + quad) ^ (r & 7);
                bfr[nt] = *(const bf16x8*)(&Bs[cur][r * BK + u * 8]);
            }
            #pragma unroll
            for (int mt = 0; mt < 4; ++mt)
                #pragma unroll
                for (int nt = 0; nt < 4; ++nt)
                    acc[mt][nt] = __builtin_amdgcn_mfma_f32_16x16x32_bf16(
                        af[mt], bfr[nt], acc[mt][nt], 0, 0, 0);
        }
        __builtin_amdgcn_s_barrier();   // all reads of buf[cur] done before overwrite
    }

    const bool isQ = (n0 < 512);
    #pragma unroll
    for (int mt = 0; mt < 4; ++mt) {
        #pragma unroll
        for (int r = 0; r < 4; ++r) {
            const int row = m0 + wm + mt * 16 + quad * 4 + r;
            if (row >= M) continue;
            #pragma unroll
            for (int nt = 0; nt < 4; ++nt) {
                const int cg = n0 + wn + nt * 16 + col;
                const float v = acc[mt][nt][r];
                if (isQ) Cq[(size_t)row * 512 + cg] = v * 0.125f;
                else     Ckv[(size_t)row * 1024 + (cg - 512)] = __float2bfloat16(v);
            }
        }
    }
}

// ---------------------------------------------------------------------------
// out-proj GEMM (R17): BM=BN=64, 584 blocks, XCD-chunked, dbuf + vmcnt(4).
// ---------------------------------------------------------------------------
__global__ __launch_bounds__(256)
void gemm_out(const __hip_bfloat16* __restrict__ A, const __hip_bfloat16* __restrict__ Bt,
              float* __restrict__ C, int M, const float* __restrict__ bias)
{
    constexpr int BM = 64, BN = 64, BK = 64, K = 512;
    __shared__ __align__(16) short As[2][BM * BK];
    __shared__ __align__(16) short Bs[2][BN * BK];

    const int tid  = threadIdx.x;
    const int bid  = blockIdx.x;
    const int L    = (bid & 7) * 73 + (bid >> 3);   // 584 = 8*73 exact
    const int m0   = (L >> 3) * BM;
    const int n0   = (L & 7) * BN;
    const int lane = tid & 63;
    const int wave = tid >> 6;
    const int wm   = (wave >> 1) * 32;
    const int wn   = (wave & 1) * 32;
    const int col  = lane & 15;
    const int quad = lane >> 4;

    f32x4 acc[2][2] = {};

    auto stage = [&](int buf, int k0) {
        #pragma unroll
        for (int it = 0; it < 2; ++it) {
            const int idx = it * 256 + tid;
            const int r   = idx >> 3;
            const int u   = (idx & 7) ^ (r & 7);
            const int gm  = (m0 + r < M) ? (m0 + r) : (M - 1);
            const __hip_bfloat16* gp = A + (size_t)gm * K + k0 + u * 8;
            __builtin_amdgcn_global_load_lds(
                (gas_ptr)gp, (las_ptr)&As[buf][(it * 256 + wave * 64) * 8], 16, 0, 0);
        }
        #pragma unroll
        for (int it = 0; it < 2; ++it) {
            const int idx = it * 256 + tid;
            const int r   = idx >> 3;
            const int u   = (idx & 7) ^ (r & 7);
            const __hip_bfloat16* gp = Bt + (size_t)(n0 + r) * K + k0 + u * 8;
            __builtin_amdgcn_global_load_lds(
                (gas_ptr)gp, (las_ptr)&Bs[buf][(it * 256 + wave * 64) * 8], 16, 0, 0);
        }
    };

    stage(0, 0);

    #pragma unroll
    for (int t = 0; t < K / BK; ++t) {
        const int cur = t & 1;
        if (t + 1 < K / BK) {
            stage(cur ^ 1, (t + 1) * BK);
            asm volatile("s_waitcnt vmcnt(4)" ::: "memory");
        } else {
            asm volatile("s_waitcnt vmcnt(0)" ::: "memory");
        }
        __builtin_amdgcn_s_barrier();

        #pragma unroll
        for (int ks = 0; ks < 2; ++ks) {
            bf16x8 af[2], bfr[2];
            #pragma unroll
            for (int mt = 0; mt < 2; ++mt) {
                const int r = wm + mt * 16 + col;
                const int u = (ks * 4 + quad) ^ (r & 7);
                af[mt] = *(const bf16x8*)(&As[cur][r * BK + u * 8]);
            }
            #pragma unroll
            for (int nt = 0; nt < 2; ++nt) {
                const int r = wn + nt * 16 + col;
                const int u = (ks * 4 + quad) ^ (r & 7);
                bfr[nt] = *(const bf16x8*)(&Bs[cur][r * BK + u * 8]);
            }
            #pragma unroll
            for (int mt = 0; mt < 2; ++mt)
                #pragma unroll
                for (int nt = 0; nt < 2; ++nt)
                    acc[mt][nt] = __builtin_amdgcn_mfma_f32_16x16x32_bf16(
                        af[mt], bfr[nt], acc[mt][nt], 0, 0, 0);
        }
        __builtin_amdgcn_s_barrier();
    }

    #pragma unroll
    for (int mt = 0; mt < 2; ++mt) {
        #pragma unroll
        for (int r = 0; r < 4; ++r) {
            const int row = m0 + wm + mt * 16 + quad * 4 + r;
            if (row >= M) continue;
            #pragma unroll
            for (int nt = 0; nt < 2; ++nt) {
                const int cg = n0 + wn + nt * 16 + col;
                C[(size_t)row * 512 + cg] = acc[mt][nt][r] + bias[cg];
            }
        }
    }
}

// ---------------------------------------------------------------------------
// Attention v7: 2 queries/wave K/V sharing (v6) with the spill removed:
// raw masked scores written straight to LDS during QK^T (s==0 lanes),
// softmax computed IN LDS (64 threads, one per (q,g)), then mix + PV
// exactly as v6 (refcheck-passed). Phase-1 register live set ~80 -> no
// scratch at (256,3). 576 blocks = 8x72 exact XCD chunks.
// ---------------------------------------------------------------------------
#define ISSUE_G(G, DST, OFF)                                                \
    { const int di = (G) / 3, dj = (G) % 3;                                 \
      const int tt = t + di - 2, yy = y + dj - 2;                           \
      _Pragma("unroll")                                                     \
      for (int e = 0; e < 4; ++e) {                                         \
        const int xx = x0 - 2 + e;                                          \
        const bool v = (tt >= 0) && (yy >= 0) && (xx >= 0);                 \
        const int row = v ? 1 + tt * SDIM * SDIM + yy * SDIM + xx : 0;      \
        DST[e] = *(const ushort8*)(KVb + (size_t)row * 1024 + (OFF) + lane * 8); \
      } }

#define DOTS_G(G, SRC)                                                      \
    { const int di = (G) / 3, dj = (G) % 3;                                 \
      const int tt = t + di - 2, yy = y + dj - 2;                           \
      const bool pv = (tt >= 0) && (yy >= 0);                               \
      _Pragma("unroll")                                                     \
      for (int dk = 0; dk < 3; ++dk) {                                      \
        const int j = 1 + (G) * 3 + dk;                                     \
        const float bias = a1[di] + a2[dj] + a3[dk];                        \
        float p0 = 0.f, p1 = 0.f;                                           \
        _Pragma("unroll")                                                   \
        for (int e = 0; e < 8; ++e) {                                       \
          p0 += bf2f(SRC[dk][e])     * qf0[e];                              \
          p1 += bf2f(SRC[dk + 1][e]) * qf1[e];                              \
        }                                                                   \
        p0 += __shfl_xor(p0, 1); p0 += __shfl_xor(p0, 2); p0 += __shfl_xor(p0, 4); \
        p1 += __shfl_xor(p1, 1); p1 += __shfl_xor(p1, 2); p1 += __shfl_xor(p1, 4); \
        if (s == 0) {                                                       \
          attn_s[wave * 2 + 0][g * NJ + j] =                                \
              (pv && (x0 - 2 + dk >= 0)) ? p0 + bias : -1e30f;              \
          attn_s[wave * 2 + 1][g * NJ + j] =                                \
              (pv && (x0 - 1 + dk >= 0)) ? p1 + bias : -1e30f;              \
        }                                                                   \
      } }

#define ACC_G(G, SRC)                                                       \
    { const int di = (G) / 3, dj = (G) % 3;                                 \
      const int tt = t + di - 2, yy = y + dj - 2;                           \
      const bool pv = (tt >= 0) && (yy >= 0);                               \
      _Pragma("unroll")                                                     \
      for (int dk = 0; dk < 3; ++dk) {                                      \
        const int j = 1 + (G) * 3 + dk;                                     \
        const float w0 = (pv && (x0 - 2 + dk >= 0)) ? mx0[j] : 0.f;         \
        const float w1 = (pv && (x0 - 1 + dk >= 0)) ? mx1[j] : 0.f;         \
        _Pragma("unroll")                                                   \
        for (int e = 0; e < 8; ++e) {                                       \
          acc0[e] += w0 * bf2f(SRC[dk][e]);                                 \
          acc1[e] += w1 * bf2f(SRC[dk + 1][e]);                             \
        }                                                                   \
      } }

__global__ __launch_bounds__(256, 3)
void attn_v7(const float* __restrict__ Q, const __hip_bfloat16* __restrict__ KVb,
             __hip_bfloat16* __restrict__ O,
             const float* __restrict__ W_th,
             const float* __restrict__ ax1, const float* __restrict__ ax2,
             const float* __restrict__ ax3)
{
    __shared__ float attn_s[8][NH * NJ];
    __shared__ float mixed_s[8][NH * NJ];

    const int tid  = threadIdx.x;
    const int wave = tid >> 6;
    const int lane = tid & 63;
    const int g    = lane >> 3;
    const int s    = lane & 7;
    const int bsw  = (blockIdx.x & 7) * 72 + (blockIdx.x >> 3);  // 576=8*72
    const int q0   = __builtin_amdgcn_readfirstlane(bsw * 8 + wave * 2);
    const int q1   = q0 + 1;

    const int t  = q0 / (SDIM * SDIM);
    const int rm = q0 % (SDIM * SDIM);
    const int y  = rm / SDIM;
    const int x0 = rm % SDIM;          // even; q1 shares t,y with x0+1 (<=23)

    float qf0[8], qf1[8];
    {
        const float4 a = *(const float4*)(Q + (size_t)(q0 + 1) * DM + lane * 8);
        const float4 b = *(const float4*)(Q + (size_t)(q0 + 1) * DM + lane * 8 + 4);
        qf0[0] = a.x; qf0[1] = a.y; qf0[2] = a.z; qf0[3] = a.w;
        qf0[4] = b.x; qf0[5] = b.y; qf0[6] = b.z; qf0[7] = b.w;
        const float4 c = *(const float4*)(Q + (size_t)(q1 + 1) * DM + lane * 8);
        const float4 d = *(const float4*)(Q + (size_t)(q1 + 1) * DM + lane * 8 + 4);
        qf1[0] = c.x; qf1[1] = c.y; qf1[2] = c.z; qf1[3] = c.w;
        qf1[4] = d.x; qf1[5] = d.y; qf1[6] = d.z; qf1[7] = d.w;
    }
    float a1[3], a2[3], a3[3];
    #pragma unroll
    for (int d = 0; d < 3; ++d) {
        a1[d] = ax1[d * NH + g];
        a2[d] = ax2[d * NH + g];
        a3[d] = ax3[d * NH + g];
    }

    // ---- Phase 1: QK^T over 9 groups + bos; raw scores -> LDS -------------
    ushort8 bufA[4], bufB[4];
    ushort8 kbos = *(const ushort8*)(KVb + lane * 8);
    ISSUE_G(0, bufA, 0);
    ISSUE_G(1, bufB, 0);
    {   // bos scores (j = 0)
        float p0 = 0.f, p1 = 0.f;
        #pragma unroll
        for (int e = 0; e < 8; ++e) {
            p0 += bf2f(kbos[e]) * qf0[e];
            p1 += bf2f(kbos[e]) * qf1[e];
        }
        p0 += __shfl_xor(p0, 1); p0 += __shfl_xor(p0, 2); p0 += __shfl_xor(p0, 4);
        p1 += __shfl_xor(p1, 1); p1 += __shfl_xor(p1, 2); p1 += __shfl_xor(p1, 4);
        if (s == 0) {
            attn_s[wave * 2 + 0][g * NJ + 0] = p0;
            attn_s[wave * 2 + 1][g * NJ + 0] = p1;
        }
    }
    DOTS_G(0, bufA);  ISSUE_G(2, bufA, 0);
    DOTS_G(1, bufB);  ISSUE_G(3, bufB, 0);
    DOTS_G(2, bufA);  ISSUE_G(4, bufA, 0);
    DOTS_G(3, bufB);  ISSUE_G(5, bufB, 0);
    DOTS_G(4, bufA);  ISSUE_G(6, bufA, 0);
    DOTS_G(5, bufB);  ISSUE_G(7, bufB, 0);
    DOTS_G(6, bufA);  ISSUE_G(8, bufA, 0);
    DOTS_G(7, bufB);
    DOTS_G(8, bufA);

    // ---- pre-issue V group 0 + vbos (hides under softmax + mix) -----------
    ushort8 vbos = *(const ushort8*)(KVb + 512 + lane * 8);
    ISSUE_G(0, bufB, 512);

    asm volatile("s_waitcnt lgkmcnt(0)" ::: "memory");
    __builtin_amdgcn_s_barrier();

    // ---- softmax in LDS: one thread per (q, g) pair (64 threads) ----------
    if (tid < 64) {
        float* row = &attn_s[tid >> 3][(tid & 7) * NJ];
        float m = -1e30f;
        #pragma unroll
        for (int j = 0; j < NJ; ++j) m = fmaxf(m, row[j]);
        float ss = 0.f;
        #pragma unroll
        for (int j = 0; j < NJ; ++j) { const float e = __expf(row[j] - m); row[j] = e; ss += e; }
        const float inv = 1.f / ss;
        #pragma unroll
        for (int j = 0; j < NJ; ++j) row[j] *= inv;
    }
    asm volatile("s_waitcnt lgkmcnt(0)" ::: "memory");
    __builtin_amdgcn_s_barrier();

    // ---- head mix (v6-identical) ------------------------------------------
    if (tid < NH * NJ) {
        const int h = tid / NJ, j = tid % NJ;
        #pragma unroll
        for (int q = 0; q < 8; ++q) {
            float acc = 0.f;
            #pragma unroll
            for (int gg = 0; gg < NH; ++gg)
                acc += W_th[h * NH + gg] * attn_s[q][gg * NJ + j];
            mixed_s[q][h * NJ + j] = acc;
        }
    }
    asm volatile("s_waitcnt lgkmcnt(0)" ::: "memory");
    __builtin_amdgcn_s_barrier();

    // ---- Phase 2: PV, pipelined (V group 0 already in flight in bufB) -----
    const float* mx0 = &mixed_s[wave * 2 + 0][g * NJ];
    const float* mx1 = &mixed_s[wave * 2 + 1][g * NJ];
    float acc0[8] = {}, acc1[8] = {};
    {   // bos contribution (j = 0)
        const float w0 = mx0[0], w1 = mx1[0];
        #pragma unroll
        for (int e = 0; e < 8; ++e) {
            acc0[e] += w0 * bf2f(vbos[e]);
            acc1[e] += w1 * bf2f(vbos[e]);
        }
    }
    ISSUE_G(1, bufA, 512);
    ACC_G(0, bufB);  ISSUE_G(2, bufB, 512);
    ACC_G(1, bufA);  ISSUE_G(3, bufA, 512);
    ACC_G(2, bufB);  ISSUE_G(4, bufB, 512);
    ACC_G(3, bufA);  ISSUE_G(5, bufA, 512);
    ACC_G(4, bufB);  ISSUE_G(6, bufB, 512);
    ACC_G(5, bufA);  ISSUE_G(7, bufA, 512);
    ACC_G(6, bufB);  ISSUE_G(8, bufB, 512);
    ACC_G(7, bufA);
    ACC_G(8, bufB);

    unsigned short o0[8], o1[8];
    #pragma unroll
    for (int e = 0; e < 8; ++e) { o0[e] = f2bf(acc0[e]); o1[e] = f2bf(acc1[e]); }
    *(ushort8*)(O + (size_t)(q0 + 1) * DM + lane * 8) = *(const ushort8*)o0;
    *(ushort8*)(O + (size_t)(q1 + 1) * DM + lane * 8) = *(const ushort8*)o1;

    if (q0 == 0) {
        unsigned short ob[8];
        #pragma unroll
        for (int e = 0; e < 8; ++e) ob[e] = (unsigned short)vbos[e];
        *(ushort8*)(O + lane * 8) = *(const ushort8*)ob;
    }
}

// ---------------------------------------------------------------------------
extern "C" void kernel_launch(void* const* d_in, const int* in_sizes, int n_in,
                              void* d_out, int out_size, void* d_ws, size_t ws_size,
                              hipStream_t stream)
{
    const float* x    = (const float*)d_in[0];
    const float* Wq   = (const float*)d_in[1];
    const float* Wkv  = (const float*)d_in[2];
    const float* W_th = (const float*)d_in[3];
    const float* Wout = (const float*)d_in[4];
    const float* bout = (const float*)d_in[5];
    const float* ax1  = (const float*)d_in[6];
    const float* ax2  = (const float*)d_in[7];
    const float* ax3  = (const float*)d_in[8];
    float* out = (float*)d_out;

    char* p = (char*)d_ws;
    float* Qf = (float*)p;                       p += (size_t)NTOK * DM * 4;
    __hip_bfloat16* KVb   = (__hip_bfloat16*)p;  p += (size_t)NTOK * 2 * DM * 2;
    __hip_bfloat16* Ob    = (__hip_bfloat16*)p;  p += (size_t)NTOK * DM * 2;
    __hip_bfloat16* Wqkvt = (__hip_bfloat16*)p;  p += (size_t)3 * DM * DM * 2;
    __hip_bfloat16* Woutt = (__hip_bfloat16*)p;  p += (size_t)DM * DM * 2;
    __hip_bfloat16* xb    = (__hip_bfloat16*)p;  p += (size_t)NTOK * DM * 2;

    const dim3 blk(256);

    prep_w<<<2177, blk, 0, stream>>>(Wq, Wkv, Wout, x, Wqkvt, Woutt, xb);

    gemm_qkv<<<444, blk, 0, stream>>>(xb, Wqkvt, Qf, KVb, NTOK);

    attn_v7<<<576, blk, 0, stream>>>(Qf, KVb, Ob, W_th, ax1, ax2, ax3);

    gemm_out<<<584, blk, 0, stream>>>(Ob, Woutt, out, NTOK, bout);
}

// Round 16
// 121.891 us; speedup vs baseline: 1.1959x; 1.1959x over previous
//
#include <hip/hip_runtime.h>
#include <hip/hip_bf16.h>

// Sparse 3DNA (causal), MI355X. Round 23: REVERT to the best-measured
// configuration (R17, 121.9us = Round-10 bench). The 2-query attn variants
// (v6/v7) both hit an opaque register-spill (~69MB scratch writes) that
// survived moving sim to LDS; line of attack abandoned. This is the
// byte-identical proven kernel: prep + dbuf/counted-vmcnt GEMMs +
// pipelined-batch attn_v5.

constexpr int TFR   = 8;
constexpr int SDIM  = 24;
constexpr int NVID  = TFR * SDIM * SDIM;   // 4608
constexpr int NTOK  = NVID + 1;            // 4609
constexpr int NH    = 8;
constexpr int DM    = 512;
constexpr int NJ    = 28;

typedef __attribute__((ext_vector_type(8))) short bf16x8;
typedef __attribute__((ext_vector_type(8))) unsigned short ushort8;
typedef __attribute__((ext_vector_type(4))) float f32x4;

typedef const __attribute__((address_space(1))) unsigned int* gas_ptr;
typedef __attribute__((address_space(3))) unsigned int* las_ptr;

__device__ __forceinline__ float bf2f(unsigned short u) {
    return __uint_as_float((unsigned)u << 16);
}
__device__ __forceinline__ unsigned short f2bf(float f) {
    __hip_bfloat16 h = __float2bfloat16(f);
    return reinterpret_cast<unsigned short&>(h);
}

// ---------------------------------------------------------------------------
// prep: transpose+cast Wq/Wkv and Wout; straight cast x -> xb (bf16).
// ---------------------------------------------------------------------------
__global__ __launch_bounds__(256)
void prep_w(const float* __restrict__ Wq, const float* __restrict__ Wkv,
            const float* __restrict__ Wout, const float* __restrict__ x,
            __hip_bfloat16* __restrict__ Wqkvt, __hip_bfloat16* __restrict__ Woutt,
            __hip_bfloat16* __restrict__ xb)
{
    const int tid = threadIdx.x;
    int tb = blockIdx.x;

    if (tb >= 1024) {                       // ---- x cast: fp32 -> bf16 ----
        const size_t base = (size_t)(tb - 1024) * 2048 + (size_t)tid * 8;
        if (base < (size_t)NTOK * DM) {
            const float4 f0 = *(const float4*)(x + base);
            const float4 f1 = *(const float4*)(x + base + 4);
            unsigned short v[8] = { f2bf(f0.x), f2bf(f0.y), f2bf(f0.z), f2bf(f0.w),
                                    f2bf(f1.x), f2bf(f1.y), f2bf(f1.z), f2bf(f1.w) };
            *(ushort8*)(xb + base) = *(const ushort8*)v;
        }
        return;
    }

    __shared__ float t[32][33];
    const float* W; __hip_bfloat16* Wt; int Nd, tX, rowOff;
    if (tb < 256)      { W = Wq;   Wt = Wqkvt; Nd = 512;  tX = 16; rowOff = 0;   }
    else if (tb < 768) { tb -= 256; W = Wkv;  Wt = Wqkvt; Nd = 1024; tX = 32; rowOff = 512; }
    else               { tb -= 768; W = Wout; Wt = Woutt; Nd = 512;  tX = 16; rowOff = 0;   }
    const int n0 = (tb % tX) * 32, k0 = (tb / tX) * 32;
    const int r  = tid >> 3;
    const int c4 = (tid & 7) * 4;
    const float4 v = *(const float4*)(W + (size_t)(k0 + r) * Nd + n0 + c4);
    t[r][c4 + 0] = v.x; t[r][c4 + 1] = v.y; t[r][c4 + 2] = v.z; t[r][c4 + 3] = v.w;
    __syncthreads();
    #pragma unroll
    for (int j = 0; j < 4; ++j)
        Wt[(size_t)(rowOff + n0 + r) * 512 + k0 + c4 + j] = __float2bfloat16(t[c4 + j][r]);
}

// ---------------------------------------------------------------------------
// QKV GEMM: BM=BN=128, BK=64, 444 blocks, XCD-chunked. Double-buffered LDS
// with raw s_barrier + counted vmcnt(8).
// ---------------------------------------------------------------------------
__global__ __launch_bounds__(256)
void gemm_qkv(const __hip_bfloat16* __restrict__ Ab, const __hip_bfloat16* __restrict__ Bt,
              float* __restrict__ Cq, __hip_bfloat16* __restrict__ Ckv, int M)
{
    constexpr int BM = 128, BN = 128, BK = 64, K = 512;
    __shared__ __align__(16) short As[2][BM * BK];
    __shared__ __align__(16) short Bs[2][BN * BK];

    const int tid  = threadIdx.x;
    const int bid  = blockIdx.x;
    const int xcd  = bid & 7, pos = bid >> 3;
    const int L    = (xcd < 4) ? xcd * 56 + pos : 224 + (xcd - 4) * 55 + pos;
    const int m0   = (L / 12) * BM;
    const int n0   = (L % 12) * BN;

    const int lane = tid & 63;
    const int wave = tid >> 6;
    const int wm   = (wave >> 1) * 64;
    const int wn   = (wave & 1) * 64;
    const int col  = lane & 15;
    const int quad = lane >> 4;

    f32x4 acc[4][4] = {};

    auto stage = [&](int buf, int k0) {
        #pragma unroll
        for (int it = 0; it < 4; ++it) {
            const int idx = it * 256 + tid;
            const int r   = idx >> 3;
            const int u   = (idx & 7) ^ (r & 7);
            const int gm  = (m0 + r < M) ? (m0 + r) : (M - 1);
            const __hip_bfloat16* gp = Ab + (size_t)gm * K + k0 + u * 8;
            __builtin_amdgcn_global_load_lds(
                (gas_ptr)gp, (las_ptr)&As[buf][(it * 256 + wave * 64) * 8], 16, 0, 0);
        }
        #pragma unroll
        for (int it = 0; it < 4; ++it) {
            const int idx = it * 256 + tid;
            const int r   = idx >> 3;
            const int u   = (idx & 7) ^ (r & 7);
            const __hip_bfloat16* gp = Bt + (size_t)(n0 + r) * K + k0 + u * 8;
            __builtin_amdgcn_global_load_lds(
                (gas_ptr)gp, (las_ptr)&Bs[buf][(it * 256 + wave * 64) * 8], 16, 0, 0);
        }
    };

    stage(0, 0);

    #pragma unroll
    for (int t = 0; t < K / BK; ++t) {
        const int cur = t & 1;
        if (t + 1 < K / BK) {
            stage(cur ^ 1, (t + 1) * BK);
            asm volatile("s_waitcnt vmcnt(8)" ::: "memory");   // cur's loads done
        } else {
            asm volatile("s_waitcnt vmcnt(0)" ::: "memory");
        }
        __builtin_amdgcn_s_barrier();

        #pragma unroll
        for (int ks = 0; ks < 2; ++ks) {
            bf16x8 af[4], bfr[4];
            #pragma unroll
            for (int mt = 0; mt < 4; ++mt) {
                const int r = wm + mt * 16 + col;
                const int u = (ks * 4 + quad) ^ (r & 7);
                af[mt] = *(const bf16x8*)(&As[cur][r * BK + u * 8]);
            }
            #pragma unroll
            for (int nt = 0; nt < 4; ++nt) {
                const int r = wn + nt * 16 + col;
                const int u = (ks * 4 + quad) ^ (r & 7);
                bfr[nt] = *(const bf16x8*)(&Bs[cur][r * BK + u * 8]);
            }
            #pragma unroll
            for (int mt = 0; mt < 4; ++mt)
                #pragma unroll
                for (int nt = 0; nt < 4; ++nt)
                    acc[mt][nt] = __builtin_amdgcn_mfma_f32_16x16x32_bf16(
                        af[mt], bfr[nt], acc[mt][nt], 0, 0, 0);
        }
        __builtin_amdgcn_s_barrier();   // all reads of buf[cur] done before overwrite
    }

    const bool isQ = (n0 < 512);
    #pragma unroll
    for (int mt = 0; mt < 4; ++mt) {
        #pragma unroll
        for (int r = 0; r < 4; ++r) {
            const int row = m0 + wm + mt * 16 + quad * 4 + r;
            if (row >= M) continue;
            #pragma unroll
            for (int nt = 0; nt < 4; ++nt) {
                const int cg = n0 + wn + nt * 16 + col;
                const float v = acc[mt][nt][r];
                if (isQ) Cq[(size_t)row * 512 + cg] = v * 0.125f;
                else     Ckv[(size_t)row * 1024 + (cg - 512)] = __float2bfloat16(v);
            }
        }
    }
}

// ---------------------------------------------------------------------------
// out-proj GEMM: BM=BN=64, 584 blocks, XCD-chunked, dbuf + counted vmcnt(4).
// ---------------------------------------------------------------------------
__global__ __launch_bounds__(256)
void gemm_out(const __hip_bfloat16* __restrict__ A, const __hip_bfloat16* __restrict__ Bt,
              float* __restrict__ C, int M, const float* __restrict__ bias)
{
    constexpr int BM = 64, BN = 64, BK = 64, K = 512;
    __shared__ __align__(16) short As[2][BM * BK];
    __shared__ __align__(16) short Bs[2][BN * BK];

    const int tid  = threadIdx.x;
    const int bid  = blockIdx.x;
    const int L    = (bid & 7) * 73 + (bid >> 3);   // 584 = 8*73 exact
    const int m0   = (L >> 3) * BM;
    const int n0   = (L & 7) * BN;
    const int lane = tid & 63;
    const int wave = tid >> 6;
    const int wm   = (wave >> 1) * 32;
    const int wn   = (wave & 1) * 32;
    const int col  = lane & 15;
    const int quad = lane >> 4;

    f32x4 acc[2][2] = {};

    auto stage = [&](int buf, int k0) {
        #pragma unroll
        for (int it = 0; it < 2; ++it) {
            const int idx = it * 256 + tid;
            const int r   = idx >> 3;
            const int u   = (idx & 7) ^ (r & 7);
            const int gm  = (m0 + r < M) ? (m0 + r) : (M - 1);
            const __hip_bfloat16* gp = A + (size_t)gm * K + k0 + u * 8;
            __builtin_amdgcn_global_load_lds(
                (gas_ptr)gp, (las_ptr)&As[buf][(it * 256 + wave * 64) * 8], 16, 0, 0);
        }
        #pragma unroll
        for (int it = 0; it < 2; ++it) {
            const int idx = it * 256 + tid;
            const int r   = idx >> 3;
            const int u   = (idx & 7) ^ (r & 7);
            const __hip_bfloat16* gp = Bt + (size_t)(n0 + r) * K + k0 + u * 8;
            __builtin_amdgcn_global_load_lds(
                (gas_ptr)gp, (las_ptr)&Bs[buf][(it * 256 + wave * 64) * 8], 16, 0, 0);
        }
    };

    stage(0, 0);

    #pragma unroll
    for (int t = 0; t < K / BK; ++t) {
        const int cur = t & 1;
        if (t + 1 < K / BK) {
            stage(cur ^ 1, (t + 1) * BK);
            asm volatile("s_waitcnt vmcnt(4)" ::: "memory");
        } else {
            asm volatile("s_waitcnt vmcnt(0)" ::: "memory");
        }
        __builtin_amdgcn_s_barrier();

        #pragma unroll
        for (int ks = 0; ks < 2; ++ks) {
            bf16x8 af[2], bfr[2];
            #pragma unroll
            for (int mt = 0; mt < 2; ++mt) {
                const int r = wm + mt * 16 + col;
                const int u = (ks * 4 + quad) ^ (r & 7);
                af[mt] = *(const bf16x8*)(&As[cur][r * BK + u * 8]);
            }
            #pragma unroll
            for (int nt = 0; nt < 2; ++nt) {
                const int r = wn + nt * 16 + col;
                const int u = (ks * 4 + quad) ^ (r & 7);
                bfr[nt] = *(const bf16x8*)(&Bs[cur][r * BK + u * 8]);
            }
            #pragma unroll
            for (int mt = 0; mt < 2; ++mt)
                #pragma unroll
                for (int nt = 0; nt < 2; ++nt)
                    acc[mt][nt] = __builtin_amdgcn_mfma_f32_16x16x32_bf16(
                        af[mt], bfr[nt], acc[mt][nt], 0, 0, 0);
        }
        __builtin_amdgcn_s_barrier();
    }

    #pragma unroll
    for (int mt = 0; mt < 2; ++mt) {
        #pragma unroll
        for (int r = 0; r < 4; ++r) {
            const int row = m0 + wm + mt * 16 + quad * 4 + r;
            if (row >= M) continue;
            #pragma unroll
            for (int nt = 0; nt < 2; ++nt) {
                const int cg = n0 + wn + nt * 16 + col;
                C[(size_t)row * 512 + cg] = acc[mt][nt][r] + bias[cg];
            }
        }
    }
}

// ---------------------------------------------------------------------------
// Attention v5 (proven): pipelined 7-load batches; V-batch-0 pre-issue;
// raw lgkmcnt(0)+s_barrier at head-mix.
// ---------------------------------------------------------------------------
__device__ __forceinline__ void neigh(int j, int t, int y, int x,
                                      int& row, bool& val,
                                      int& di, int& dj, int& dk)
{
    if (j == 0) { row = 0; val = true; di = 0; dj = 0; dk = 0; return; }
    const int jp = j - 1;
    di = jp / 9; dj = (jp / 3) % 3; dk = jp % 3;
    const int tt = t + di - 2, yy = y + dj - 2, xx = x + dk - 2;
    val = (tt >= 0) && (yy >= 0) && (xx >= 0);
    row = val ? 1 + tt * SDIM * SDIM + yy * SDIM + xx : 0;
}

#define ISSUE_K(B, DST)                                                     \
    { _Pragma("unroll")                                                     \
      for (int u = 0; u < 7; ++u) {                                         \
        int row; bool val; int di, dj, dk;                                  \
        neigh((B) * 7 + u, t, y, x, row, val, di, dj, dk);                  \
        DST[u] = *(const ushort8*)(KVb + (size_t)row * 1024 + lane * 8);    \
      } }

#define DOTS_K(B, SRC)                                                      \
    { _Pragma("unroll")                                                     \
      for (int u = 0; u < 7; ++u) {                                         \
        const int j = (B) * 7 + u;                                          \
        int row; bool val; int di, dj, dk;                                  \
        neigh(j, t, y, x, row, val, di, dj, dk);                            \
        float p = 0.f;                                                      \
        _Pragma("unroll")                                                   \
        for (int e = 0; e < 8; ++e) p += bf2f(SRC[u][e]) * qf[e];           \
        p += __shfl_xor(p, 1);                                              \
        p += __shfl_xor(p, 2);                                              \
        p += __shfl_xor(p, 4);                                              \
        sim[j] = !val ? -1e30f                                              \
               : (j == 0 ? p : p + a1[di] + a2[dj] + a3[dk]);               \
      } }

#define ISSUE_V(B, DST)                                                     \
    { _Pragma("unroll")                                                     \
      for (int u = 0; u < 7; ++u) {                                         \
        int row; bool val; int di, dj, dk;                                  \
        neigh((B) * 7 + u, t, y, x, row, val, di, dj, dk);                  \
        DST[u] = *(const ushort8*)(KVb + (size_t)row * 1024 + 512 + lane * 8); \
      } }

#define ACC_V(B, SRC)                                                       \
    { _Pragma("unroll")                                                     \
      for (int u = 0; u < 7; ++u) {                                         \
        const int j = (B) * 7 + u;                                          \
        const float w = mixed_s[wave][g * NJ + j];                          \
        _Pragma("unroll")                                                   \
        for (int e = 0; e < 8; ++e) acc8[e] += w * bf2f(SRC[u][e]);         \
      } }

__global__ __launch_bounds__(256, 3)
void attn_v5(const float* __restrict__ Q, const __hip_bfloat16* __restrict__ KVb,
             __hip_bfloat16* __restrict__ O,
             const float* __restrict__ W_th,
             const float* __restrict__ ax1, const float* __restrict__ ax2,
             const float* __restrict__ ax3)
{
    __shared__ float attn_s[4][NH * NJ];
    __shared__ float mixed_s[4][NH * NJ];

    const int tid  = threadIdx.x;
    const int wave = tid >> 6;
    const int lane = tid & 63;
    const int g    = lane >> 3;
    const int s    = lane & 7;
    const int bsw  = (blockIdx.x & 7) * (NVID / 4 / 8) + (blockIdx.x >> 3);
    const int i    = __builtin_amdgcn_readfirstlane(bsw * 4 + (tid >> 6));
    const int qrow = i + 1;

    const int t  = i / (SDIM * SDIM);
    const int rm = i % (SDIM * SDIM);
    const int y  = rm / SDIM;
    const int x  = rm % SDIM;

    float qf[8];
    {
        const float4 q0 = *(const float4*)(Q + (size_t)qrow * DM + lane * 8);
        const float4 q1 = *(const float4*)(Q + (size_t)qrow * DM + lane * 8 + 4);
        qf[0] = q0.x; qf[1] = q0.y; qf[2] = q0.z; qf[3] = q0.w;
        qf[4] = q1.x; qf[5] = q1.y; qf[6] = q1.z; qf[7] = q1.w;
    }
    float a1[3], a2[3], a3[3];
    #pragma unroll
    for (int d = 0; d < 3; ++d) {
        a1[d] = ax1[d * NH + g];
        a2[d] = ax2[d * NH + g];
        a3[d] = ax3[d * NH + g];
    }

    // ---- Phase 1: QK^T, pipelined batches ---------------------------------
    float sim[NJ];
    ushort8 bufA[7], bufB[7];
    ISSUE_K(0, bufA);
    ISSUE_K(1, bufB);
    DOTS_K(0, bufA);
    ISSUE_K(2, bufA);
    DOTS_K(1, bufB);
    ISSUE_K(3, bufB);
    DOTS_K(2, bufA);
    DOTS_K(3, bufB);

    // ---- pre-issue V batch 0 (hides under softmax + mix barriers) ---------
    ISSUE_V(0, bufA);

    // ---- softmax (per head, in registers) ---------------------------------
    float m = -1e30f;
    #pragma unroll
    for (int j = 0; j < NJ; ++j) m = fmaxf(m, sim[j]);
    float ssum = 0.f;
    #pragma unroll
    for (int j = 0; j < NJ; ++j) { sim[j] = __expf(sim[j] - m); ssum += sim[j]; }
    const float inv = 1.f / ssum;
    #pragma unroll
    for (int j = 0; j < NJ; ++j) sim[j] *= inv;

    // ---- head mix via LDS; raw barriers (no vmcnt drain) ------------------
    if (s == 0) {
        #pragma unroll
        for (int u = 0; u < 7; ++u) {
            f32x4 v4 = { sim[4*u], sim[4*u+1], sim[4*u+2], sim[4*u+3] };
            *(f32x4*)(&attn_s[wave][g * NJ + 4 * u]) = v4;
        }
    }
    asm volatile("s_waitcnt lgkmcnt(0)" ::: "memory");
    __builtin_amdgcn_s_barrier();

    if (tid < NH * NJ) {
        const int h = tid / NJ, j = tid % NJ;
        #pragma unroll
        for (int q = 0; q < 4; ++q) {
            float acc = 0.f;
            #pragma unroll
            for (int gg = 0; gg < NH; ++gg)
                acc += W_th[h * NH + gg] * attn_s[q][gg * NJ + j];
            mixed_s[q][h * NJ + j] = acc;
        }
    }
    asm volatile("s_waitcnt lgkmcnt(0)" ::: "memory");
    __builtin_amdgcn_s_barrier();

    // ---- Phase 2: PV, pipelined (batch 0 already in flight) ---------------
    float acc8[8] = {};
    ISSUE_V(1, bufB);
    ACC_V(0, bufA);
    ISSUE_V(2, bufA);
    ACC_V(1, bufB);
    ISSUE_V(3, bufB);
    ACC_V(2, bufA);
    ACC_V(3, bufB);

    unsigned short o[8];
    #pragma unroll
    for (int e = 0; e < 8; ++e) o[e] = f2bf(acc8[e]);
    *(ushort8*)(O + (size_t)qrow * DM + lane * 8) = *(const ushort8*)o;

    if (i == 0) {
        const ushort8 vb0 = *(const ushort8*)(KVb + 512 + lane * 8);
        *(ushort8*)(O + lane * 8) = vb0;
    }
}

// ---------------------------------------------------------------------------
extern "C" void kernel_launch(void* const* d_in, const int* in_sizes, int n_in,
                              void* d_out, int out_size, void* d_ws, size_t ws_size,
                              hipStream_t stream)
{
    const float* x    = (const float*)d_in[0];
    const float* Wq   = (const float*)d_in[1];
    const float* Wkv  = (const float*)d_in[2];
    const float* W_th = (const float*)d_in[3];
    const float* Wout = (const float*)d_in[4];
    const float* bout = (const float*)d_in[5];
    const float* ax1  = (const float*)d_in[6];
    const float* ax2  = (const float*)d_in[7];
    const float* ax3  = (const float*)d_in[8];
    float* out = (float*)d_out;

    char* p = (char*)d_ws;
    float* Qf = (float*)p;                       p += (size_t)NTOK * DM * 4;
    __hip_bfloat16* KVb   = (__hip_bfloat16*)p;  p += (size_t)NTOK * 2 * DM * 2;
    __hip_bfloat16* Ob    = (__hip_bfloat16*)p;  p += (size_t)NTOK * DM * 2;
    __hip_bfloat16* Wqkvt = (__hip_bfloat16*)p;  p += (size_t)3 * DM * DM * 2;
    __hip_bfloat16* Woutt = (__hip_bfloat16*)p;  p += (size_t)DM * DM * 2;
    __hip_bfloat16* xb    = (__hip_bfloat16*)p;  p += (size_t)NTOK * DM * 2;

    const dim3 blk(256);

    prep_w<<<2177, blk, 0, stream>>>(Wq, Wkv, Wout, x, Wqkvt, Woutt, xb);

    gemm_qkv<<<444, blk, 0, stream>>>(xb, Wqkvt, Qf, KVb, NTOK);

    attn_v5<<<dim3(NVID / 4), blk, 0, stream>>>(Qf, KVb, Ob, W_th, ax1, ax2, ax3);

    gemm_out<<<584, blk, 0, stream>>>(Ob, Woutt, out, NTOK, bout);
}